// Round 1
// baseline (6684.908 us; speedup 1.0000x reference)
//
#include <hip/hip_runtime.h>
#include <math.h>

#define D 256
#define EPSV 1e-8f
#define GAMMAV 0.2f

__device__ __forceinline__ float cleanf(float x) {
    if (isnan(x)) return 0.0f;
    if (isinf(x)) return x > 0.0f ? 10000.0f : 0.0001f;
    return x;
}

// ---- per-edge attention precompute ------------------------------------

__global__ __launch_bounds__(256) void k_seg_denom_cnt(
    const int* __restrict__ head, const float* __restrict__ omega,
    float* __restrict__ denom, float* __restrict__ cnt, int E) {
    int e = blockIdx.x * blockDim.x + threadIdx.x;
    if (e >= E) return;
    int h = head[e];
    atomicAdd(&denom[h], omega[e]);
    atomicAdd(&cnt[h], 1.0f);
}

__global__ __launch_bounds__(256) void k_alpha_eta0(
    const int* __restrict__ head, const float* __restrict__ omega,
    const float* __restrict__ denom, float* __restrict__ alpha,
    float* __restrict__ denom2, int E) {
    int e = blockIdx.x * blockDim.x + threadIdx.x;
    if (e >= E) return;
    int h = head[e];
    float a = omega[e] / (denom[h] + EPSV);
    alpha[e] = a;
    float e0 = (a > GAMMAV) ? a : 0.0f;
    if (e0 != 0.0f) atomicAdd(&denom2[h], e0);
}

__global__ __launch_bounds__(256) void k_eta_final(
    const int* __restrict__ head, const float* __restrict__ alpha,
    const float* __restrict__ denom2, float* __restrict__ eta, int E) {
    int e = blockIdx.x * blockDim.x + threadIdx.x;
    if (e >= E) return;
    int h = head[e];
    float a = alpha[e];
    float e0 = (a > GAMMAV) ? a : 0.0f;
    eta[e] = e0 / (denom2[h] + EPSV);
}

// ---- per-hop scatters (one wave = one edge, 64 lanes x float4) --------

__global__ __launch_bounds__(256) void k_scatter_ent(
    const int* __restrict__ head, const int* __restrict__ tail,
    const int* __restrict__ etype, const float* __restrict__ rho,
    const float* __restrict__ rel,      // (N_REL-1, D)
    const float* __restrict__ ent,      // (n_ent, D) current
    float* __restrict__ agg, int E) {
    int wave = (blockIdx.x * blockDim.x + threadIdx.x) >> 6;
    int lane = threadIdx.x & 63;
    if (wave >= E) return;
    int h = head[wave];
    int t = tail[wave];
    int r = etype[wave] - 1;
    float rv = rho[wave];
    float4 ev = ((const float4*)(ent + (size_t)t * D))[lane];
    float4 rw = ((const float4*)(rel + (size_t)r * D))[lane];
    float* out = agg + (size_t)h * D + lane * 4;
    atomicAdd(out + 0, rv * ev.x * rw.x);
    atomicAdd(out + 1, rv * ev.y * rw.y);
    atomicAdd(out + 2, rv * ev.z * rw.z);
    atomicAdd(out + 3, rv * ev.w * rw.w);
}

__global__ __launch_bounds__(256) void k_scatter_usr(
    const int* __restrict__ iu, const int* __restrict__ ii,
    const float* __restrict__ w, const float* __restrict__ ent,
    float* __restrict__ agg, int IE) {
    int wave = (blockIdx.x * blockDim.x + threadIdx.x) >> 6;
    int lane = threadIdx.x & 63;
    if (wave >= IE) return;
    int u = iu[wave];
    int it = ii[wave];
    float wv = w[wave];
    float4 ev = ((const float4*)(ent + (size_t)it * D))[lane];
    float* out = agg + (size_t)u * D + lane * 4;
    atomicAdd(out + 0, wv * ev.x);
    atomicAdd(out + 1, wv * ev.y);
    atomicAdd(out + 2, wv * ev.z);
    atomicAdd(out + 3, wv * ev.w);
}

// ---- per-hop row normalize + residual (one wave = one row) ------------

__global__ __launch_bounds__(256) void k_norm_ent(
    float* __restrict__ agg, const float* __restrict__ cnt,
    float* __restrict__ cur, float* __restrict__ res, int n) {
    int row = (blockIdx.x * blockDim.x + threadIdx.x) >> 6;
    int lane = threadIdx.x & 63;
    if (row >= n) return;
    float c = cnt[row];
    if (c < 1.0f) c = 1.0f;
    float4* ap = (float4*)(agg + (size_t)row * D);
    float4 v = ap[lane];
    v.x /= c; v.y /= c; v.z /= c; v.w /= c;
    float ss = v.x * v.x + v.y * v.y + v.z * v.z + v.w * v.w;
    #pragma unroll
    for (int o = 32; o >= 1; o >>= 1) ss += __shfl_down(ss, o);
    ss = __shfl(ss, 0);
    float nrm = sqrtf(ss);
    float dn = (nrm > EPSV) ? nrm : EPSV;
    float4 y;
    y.x = cleanf(v.x / dn);
    y.y = cleanf(v.y / dn);
    y.z = cleanf(v.z / dn);
    y.w = cleanf(v.w / dn);
    float4* cp = (float4*)(cur + (size_t)row * D);
    float4* rp = (float4*)(res + (size_t)row * D);
    float4 rv = rp[lane];
    rv.x += y.x; rv.y += y.y; rv.z += y.z; rv.w += y.w;
    rp[lane] = rv;
    cp[lane] = y;
    ap[lane] = make_float4(0.f, 0.f, 0.f, 0.f);  // re-zero for next hop
}

__global__ __launch_bounds__(256) void k_norm_usr(
    float* __restrict__ agg, float* __restrict__ res, int n) {
    int row = (blockIdx.x * blockDim.x + threadIdx.x) >> 6;
    int lane = threadIdx.x & 63;
    if (row >= n) return;
    float4* ap = (float4*)(agg + (size_t)row * D);
    float4 v = ap[lane];
    float ss = v.x * v.x + v.y * v.y + v.z * v.z + v.w * v.w;
    #pragma unroll
    for (int o = 32; o >= 1; o >>= 1) ss += __shfl_down(ss, o);
    ss = __shfl(ss, 0);
    float nrm = sqrtf(ss);
    float dn = (nrm > EPSV) ? nrm : EPSV;
    float4 y;
    y.x = cleanf(v.x / dn);
    y.y = cleanf(v.y / dn);
    y.z = cleanf(v.z / dn);
    y.w = cleanf(v.w / dn);
    float4* rp = (float4*)(res + (size_t)row * D);
    float4 rv = rp[lane];
    rv.x += y.x; rv.y += y.y; rv.z += y.z; rv.w += y.w;
    rp[lane] = rv;
    ap[lane] = make_float4(0.f, 0.f, 0.f, 0.f);
}

extern "C" void kernel_launch(void* const* d_in, const int* in_sizes, int n_in,
                              void* d_out, int out_size, void* d_ws, size_t ws_size,
                              hipStream_t stream) {
    const float* user_emb   = (const float*)d_in[0];
    const float* entity_emb = (const float*)d_in[1];
    const int*   edge_index = (const int*)d_in[2];
    const int*   edge_type  = (const int*)d_in[3];
    const float* omega      = (const float*)d_in[4];
    const int*   inter_edge = (const int*)d_in[5];
    const float* inter_w    = (const float*)d_in[6];
    const float* rel_emb    = (const float*)d_in[7];

    const int n_users = in_sizes[0] / D;
    const int n_ent   = in_sizes[1] / D;
    const int E       = in_sizes[3];
    const int IE      = in_sizes[6];

    const int* head = edge_index;
    const int* tail = edge_index + E;
    const int* iu   = inter_edge;
    const int* ii   = inter_edge + IE;

    // ---- workspace layout ----
    char* w = (char*)d_ws;
    size_t entB = (size_t)n_ent * D * sizeof(float);
    size_t usrB = (size_t)n_users * D * sizeof(float);
    float* ent_cur = (float*)w;                 w += entB;
    float* ent_agg = (float*)w;                 w += entB;
    float* usr_agg = (float*)w;                 w += usrB;
    float* alpha   = (float*)w;                 w += (size_t)E * sizeof(float);
    float* eta     = (float*)w;                 w += (size_t)E * sizeof(float);
    float* denom   = (float*)w;                 w += (size_t)n_ent * sizeof(float);
    float* denom2  = (float*)w;                 w += (size_t)n_ent * sizeof(float);
    float* cnt     = (float*)w;                 w += (size_t)n_ent * sizeof(float);

    float* ent_res = (float*)d_out;                       // n_ent * D
    float* usr_res = (float*)d_out + (size_t)n_ent * D;   // n_users * D

    // ---- init (ws/out are poisoned every call) ----
    hipMemsetAsync(ent_agg, 0, entB, stream);
    hipMemsetAsync(usr_agg, 0, usrB, stream);
    hipMemsetAsync(denom, 0, (size_t)n_ent * sizeof(float), stream);
    hipMemsetAsync(denom2, 0, (size_t)n_ent * sizeof(float), stream);
    hipMemsetAsync(cnt, 0, (size_t)n_ent * sizeof(float), stream);
    hipMemcpyAsync(ent_cur, entity_emb, entB, hipMemcpyDeviceToDevice, stream);
    hipMemcpyAsync(ent_res, entity_emb, entB, hipMemcpyDeviceToDevice, stream);
    hipMemcpyAsync(usr_res, user_emb, usrB, hipMemcpyDeviceToDevice, stream);

    // ---- attention precompute ----
    int eb = (E + 255) / 256;
    k_seg_denom_cnt<<<eb, 256, 0, stream>>>(head, omega, denom, cnt, E);
    k_alpha_eta0<<<eb, 256, 0, stream>>>(head, omega, denom, alpha, denom2, E);
    k_eta_final<<<eb, 256, 0, stream>>>(head, alpha, denom2, eta, E);

    // ---- hops ----
    int sbE  = (E * 64 + 255) / 256;       // one wave per KG edge
    int sbI  = (IE * 64 + 255) / 256;      // one wave per interaction edge
    int nbE  = (n_ent * 64 + 255) / 256;   // one wave per entity row
    int nbU  = (n_users * 64 + 255) / 256; // one wave per user row

    for (int hop = 1; hop <= 3; ++hop) {
        const float* rho = (hop < 3) ? alpha : eta;
        k_scatter_ent<<<sbE, 256, 0, stream>>>(head, tail, edge_type, rho,
                                               rel_emb, ent_cur, ent_agg, E);
        k_scatter_usr<<<sbI, 256, 0, stream>>>(iu, ii, inter_w, ent_cur, usr_agg, IE);
        k_norm_ent<<<nbE, 256, 0, stream>>>(ent_agg, cnt, ent_cur, ent_res, n_ent);
        k_norm_usr<<<nbU, 256, 0, stream>>>(usr_agg, usr_res, n_users);
    }
}

// Round 2
// 930.895 us; speedup vs baseline: 7.1812x; 7.1812x over previous
//
#include <hip/hip_runtime.h>
#include <math.h>

#define D 256
#define EPSV 1e-8f
#define GAMMAV 0.2f
#define SCAN_B 256

__device__ __forceinline__ float cleanf(float x) {
    if (isnan(x)) return 0.0f;
    if (isinf(x)) return x > 0.0f ? 10000.0f : 0.0001f;
    return x;
}

// ---- CSR build ---------------------------------------------------------

__global__ __launch_bounds__(256) void k_count(
    const int* __restrict__ key, int* __restrict__ counts, int n) {
    int e = blockIdx.x * blockDim.x + threadIdx.x;
    if (e >= n) return;
    atomicAdd(&counts[key[e]], 1);
}

// hierarchical exclusive scan: scan1 (per-block), scan2 (block sums), scan3 (add)
__global__ __launch_bounds__(SCAN_B) void k_scan1(
    const int* __restrict__ in, int* __restrict__ out, int* __restrict__ bsums, int n) {
    __shared__ int tmp[SCAN_B];
    int i = blockIdx.x * SCAN_B + threadIdx.x;
    int v = (i < n) ? in[i] : 0;
    tmp[threadIdx.x] = v;
    __syncthreads();
    for (int o = 1; o < SCAN_B; o <<= 1) {
        int t = (threadIdx.x >= o) ? tmp[threadIdx.x - o] : 0;
        __syncthreads();
        tmp[threadIdx.x] += t;
        __syncthreads();
    }
    if (i < n) out[i] = tmp[threadIdx.x] - v;   // exclusive
    if (threadIdx.x == SCAN_B - 1) bsums[blockIdx.x] = tmp[threadIdx.x];
}

__global__ __launch_bounds__(1024) void k_scan2(int* __restrict__ bsums, int nb) {
    __shared__ int tmp[1024];
    int v = (threadIdx.x < nb) ? bsums[threadIdx.x] : 0;
    tmp[threadIdx.x] = v;
    __syncthreads();
    for (int o = 1; o < 1024; o <<= 1) {
        int t = (threadIdx.x >= o) ? tmp[threadIdx.x - o] : 0;
        __syncthreads();
        tmp[threadIdx.x] += t;
        __syncthreads();
    }
    if (threadIdx.x < nb) bsums[threadIdx.x] = tmp[threadIdx.x] - v;  // exclusive
}

__global__ __launch_bounds__(SCAN_B) void k_scan3(
    int* __restrict__ out, const int* __restrict__ bsums, int n) {
    int i = blockIdx.x * SCAN_B + threadIdx.x;
    if (i < n) out[i] += bsums[blockIdx.x];
}

__global__ __launch_bounds__(256) void k_fill_kg(
    const int* __restrict__ head, const int* __restrict__ tail,
    const int* __restrict__ etype, const float* __restrict__ omega,
    int* __restrict__ cursor, int* __restrict__ csr_tail,
    int* __restrict__ csr_rel, float* __restrict__ csr_omega, int E) {
    int e = blockIdx.x * blockDim.x + threadIdx.x;
    if (e >= E) return;
    int h = head[e];
    int p = atomicAdd(&cursor[h], 1);
    csr_tail[p]  = tail[e];
    csr_rel[p]   = etype[e] - 1;
    csr_omega[p] = omega[e];
}

__global__ __launch_bounds__(256) void k_fill_inter(
    const int* __restrict__ iu, const int* __restrict__ ii,
    const float* __restrict__ w, int* __restrict__ cursor,
    int* __restrict__ ucsr_item, float* __restrict__ ucsr_w, int IE) {
    int e = blockIdx.x * blockDim.x + threadIdx.x;
    if (e >= IE) return;
    int u = iu[e];
    int p = atomicAdd(&cursor[u], 1);
    ucsr_item[p] = ii[e];
    ucsr_w[p]    = w[e];
}

// ---- attention (alpha/eta) per head, sequential over its edges --------

__global__ __launch_bounds__(256) void k_attn(
    const int* __restrict__ offs, const int* __restrict__ counts,
    const float* __restrict__ csr_omega, float* __restrict__ csr_alpha,
    float* __restrict__ csr_eta, int n) {
    int h = blockIdx.x * blockDim.x + threadIdx.x;
    if (h >= n) return;
    int s = offs[h], deg = counts[h];
    float sum = 0.0f;
    for (int j = s; j < s + deg; ++j) sum += csr_omega[j];
    float denom = sum + EPSV;
    float sum2 = 0.0f;
    for (int j = s; j < s + deg; ++j) {
        float a = csr_omega[j] / denom;
        csr_alpha[j] = a;
        sum2 += (a > GAMMAV) ? a : 0.0f;
    }
    float denom2 = sum2 + EPSV;
    for (int j = s; j < s + deg; ++j) {
        float a = csr_alpha[j];
        float e0 = (a > GAMMAV) ? a : 0.0f;
        csr_eta[j] = e0 / denom2;
    }
}

// ---- fused gather + mean + l2norm + clean + residual ------------------
// one wave per destination row; 64 lanes x float4 = 256 dims

__global__ __launch_bounds__(256) void k_gather_ent(
    const int* __restrict__ offs, const int* __restrict__ counts,
    const int* __restrict__ csr_tail, const int* __restrict__ csr_rel,
    const float* __restrict__ rho, const float* __restrict__ rel,
    const float* __restrict__ src, float* __restrict__ dst,
    float* __restrict__ res, int n) {
    int row  = (blockIdx.x * blockDim.x + threadIdx.x) >> 6;
    int lane = threadIdx.x & 63;
    if (row >= n) return;
    int s = offs[row], deg = counts[row];
    float4 acc = make_float4(0.f, 0.f, 0.f, 0.f);
    for (int j = s; j < s + deg; ++j) {
        int t = csr_tail[j];
        int r = csr_rel[j];
        float rv = rho[j];
        float4 ev = ((const float4*)(src + (size_t)t * D))[lane];
        float4 rw = ((const float4*)(rel + (size_t)r * D))[lane];
        acc.x += rv * ev.x * rw.x;
        acc.y += rv * ev.y * rw.y;
        acc.z += rv * ev.z * rw.z;
        acc.w += rv * ev.w * rw.w;
    }
    float c = (deg > 0) ? (float)deg : 1.0f;
    acc.x /= c; acc.y /= c; acc.z /= c; acc.w /= c;
    float ss = acc.x * acc.x + acc.y * acc.y + acc.z * acc.z + acc.w * acc.w;
    #pragma unroll
    for (int o = 32; o >= 1; o >>= 1) ss += __shfl_down(ss, o);
    ss = __shfl(ss, 0);
    float nrm = sqrtf(ss);
    float dn = (nrm > EPSV) ? nrm : EPSV;
    float4 y;
    y.x = cleanf(acc.x / dn);
    y.y = cleanf(acc.y / dn);
    y.z = cleanf(acc.z / dn);
    y.w = cleanf(acc.w / dn);
    ((float4*)(dst + (size_t)row * D))[lane] = y;
    float4* rp = (float4*)(res + (size_t)row * D);
    float4 rv2 = rp[lane];
    rv2.x += y.x; rv2.y += y.y; rv2.z += y.z; rv2.w += y.w;
    rp[lane] = rv2;
}

__global__ __launch_bounds__(256) void k_gather_usr(
    const int* __restrict__ offs, const int* __restrict__ counts,
    const int* __restrict__ ucsr_item, const float* __restrict__ ucsr_w,
    const float* __restrict__ src, float* __restrict__ res, int n) {
    int row  = (blockIdx.x * blockDim.x + threadIdx.x) >> 6;
    int lane = threadIdx.x & 63;
    if (row >= n) return;
    int s = offs[row], deg = counts[row];
    float4 acc = make_float4(0.f, 0.f, 0.f, 0.f);
    for (int j = s; j < s + deg; ++j) {
        int t = ucsr_item[j];
        float wv = ucsr_w[j];
        float4 ev = ((const float4*)(src + (size_t)t * D))[lane];
        acc.x += wv * ev.x;
        acc.y += wv * ev.y;
        acc.z += wv * ev.z;
        acc.w += wv * ev.w;
    }
    float ss = acc.x * acc.x + acc.y * acc.y + acc.z * acc.z + acc.w * acc.w;
    #pragma unroll
    for (int o = 32; o >= 1; o >>= 1) ss += __shfl_down(ss, o);
    ss = __shfl(ss, 0);
    float nrm = sqrtf(ss);
    float dn = (nrm > EPSV) ? nrm : EPSV;
    float4 y;
    y.x = cleanf(acc.x / dn);
    y.y = cleanf(acc.y / dn);
    y.z = cleanf(acc.z / dn);
    y.w = cleanf(acc.w / dn);
    float4* rp = (float4*)(res + (size_t)row * D);
    float4 rv2 = rp[lane];
    rv2.x += y.x; rv2.y += y.y; rv2.z += y.z; rv2.w += y.w;
    rp[lane] = rv2;
}

extern "C" void kernel_launch(void* const* d_in, const int* in_sizes, int n_in,
                              void* d_out, int out_size, void* d_ws, size_t ws_size,
                              hipStream_t stream) {
    const float* user_emb   = (const float*)d_in[0];
    const float* entity_emb = (const float*)d_in[1];
    const int*   edge_index = (const int*)d_in[2];
    const int*   edge_type  = (const int*)d_in[3];
    const float* omega      = (const float*)d_in[4];
    const int*   inter_edge = (const int*)d_in[5];
    const float* inter_w    = (const float*)d_in[6];
    const float* rel_emb    = (const float*)d_in[7];

    const int n_users = in_sizes[0] / D;
    const int n_ent   = in_sizes[1] / D;
    const int E       = in_sizes[3];
    const int IE      = in_sizes[6];

    const int* head = edge_index;
    const int* tail = edge_index + E;
    const int* iu   = inter_edge;
    const int* ii   = inter_edge + IE;

    // ---- workspace layout (16B-aligned large arrays first) ----
    char* w = (char*)d_ws;
    size_t entB = (size_t)n_ent * D * sizeof(float);
    float* ent_a = (float*)w;  w += entB;
    float* ent_b = (float*)w;  w += entB;
    int*   counts_e = (int*)w;   w += (size_t)n_ent * sizeof(int);
    int*   offs_e   = (int*)w;   w += (size_t)n_ent * sizeof(int);
    int*   cursor_e = (int*)w;   w += (size_t)n_ent * sizeof(int);
    int*   counts_u = (int*)w;   w += (size_t)n_users * sizeof(int);
    int*   offs_u   = (int*)w;   w += (size_t)n_users * sizeof(int);
    int*   cursor_u = (int*)w;   w += (size_t)n_users * sizeof(int);
    int*   bsums_e  = (int*)w;   w += 1024 * sizeof(int);
    int*   bsums_u  = (int*)w;   w += 1024 * sizeof(int);
    int*   csr_tail = (int*)w;   w += (size_t)E * sizeof(int);
    int*   csr_rel  = (int*)w;   w += (size_t)E * sizeof(int);
    float* csr_omega = (float*)w; w += (size_t)E * sizeof(float);
    float* csr_alpha = (float*)w; w += (size_t)E * sizeof(float);
    float* csr_eta   = (float*)w; w += (size_t)E * sizeof(float);
    int*   ucsr_item = (int*)w;   w += (size_t)IE * sizeof(int);
    float* ucsr_w    = (float*)w; w += (size_t)IE * sizeof(float);

    float* ent_res = (float*)d_out;
    float* usr_res = (float*)d_out + (size_t)n_ent * D;

    size_t usrB = (size_t)n_users * D * sizeof(float);

    // ---- init ----
    hipMemsetAsync(counts_e, 0, (size_t)n_ent * sizeof(int), stream);
    hipMemsetAsync(counts_u, 0, (size_t)n_users * sizeof(int), stream);
    hipMemcpyAsync(ent_res, entity_emb, entB, hipMemcpyDeviceToDevice, stream);
    hipMemcpyAsync(usr_res, user_emb, usrB, hipMemcpyDeviceToDevice, stream);

    int eb  = (E + 255) / 256;
    int ieb = (IE + 255) / 256;

    // ---- counts ----
    k_count<<<eb, 256, 0, stream>>>(head, counts_e, E);
    k_count<<<ieb, 256, 0, stream>>>(iu, counts_u, IE);

    // ---- exclusive scans -> offsets ----
    int nbE = (n_ent + SCAN_B - 1) / SCAN_B;
    int nbU = (n_users + SCAN_B - 1) / SCAN_B;
    k_scan1<<<nbE, SCAN_B, 0, stream>>>(counts_e, offs_e, bsums_e, n_ent);
    k_scan2<<<1, 1024, 0, stream>>>(bsums_e, nbE);
    k_scan3<<<nbE, SCAN_B, 0, stream>>>(offs_e, bsums_e, n_ent);
    k_scan1<<<nbU, SCAN_B, 0, stream>>>(counts_u, offs_u, bsums_u, n_users);
    k_scan2<<<1, 1024, 0, stream>>>(bsums_u, nbU);
    k_scan3<<<nbU, SCAN_B, 0, stream>>>(offs_u, bsums_u, n_users);

    // ---- fill CSR ----
    hipMemcpyAsync(cursor_e, offs_e, (size_t)n_ent * sizeof(int),
                   hipMemcpyDeviceToDevice, stream);
    hipMemcpyAsync(cursor_u, offs_u, (size_t)n_users * sizeof(int),
                   hipMemcpyDeviceToDevice, stream);
    k_fill_kg<<<eb, 256, 0, stream>>>(head, tail, edge_type, omega, cursor_e,
                                      csr_tail, csr_rel, csr_omega, E);
    k_fill_inter<<<ieb, 256, 0, stream>>>(iu, ii, inter_w, cursor_u,
                                          ucsr_item, ucsr_w, IE);

    // ---- attention ----
    int hb = (n_ent + 255) / 256;
    k_attn<<<hb, 256, 0, stream>>>(offs_e, counts_e, csr_omega,
                                   csr_alpha, csr_eta, n_ent);

    // ---- hops (fused gather+mean+norm+clean+residual) ----
    int gbE = ((size_t)n_ent * 64 + 255) / 256;
    int gbU = ((size_t)n_users * 64 + 255) / 256;

    const float* srcs[3] = { entity_emb, ent_a, ent_b };
    float*       dsts[3] = { ent_a, ent_b, ent_a };
    for (int hop = 1; hop <= 3; ++hop) {
        const float* rho = (hop < 3) ? csr_alpha : csr_eta;
        const float* src = srcs[hop - 1];
        float*       dst = dsts[hop - 1];
        k_gather_usr<<<gbU, 256, 0, stream>>>(offs_u, counts_u, ucsr_item,
                                              ucsr_w, src, usr_res, n_users);
        k_gather_ent<<<gbE, 256, 0, stream>>>(offs_e, counts_e, csr_tail,
                                              csr_rel, rho, rel_emb, src,
                                              dst, ent_res, n_ent);
    }
}

// Round 3
// 715.907 us; speedup vs baseline: 9.3377x; 1.3003x over previous
//
#include <hip/hip_runtime.h>
#include <math.h>

#define D 256
#define EPSV 1e-8f
#define GAMMAV 0.2f
#define SCAN_B 256

__device__ __forceinline__ float cleanf(float x) {
    if (isnan(x)) return 0.0f;
    if (isinf(x)) return x > 0.0f ? 10000.0f : 0.0001f;
    return x;
}

// ---- fused counting ---------------------------------------------------

__global__ __launch_bounds__(256) void k_count_both(
    const int* __restrict__ head, const int* __restrict__ iu,
    int* __restrict__ counts_e, int* __restrict__ counts_u, int E, int IE) {
    int i = blockIdx.x * blockDim.x + threadIdx.x;
    if (i < E) {
        atomicAdd(&counts_e[head[i]], 1);
    } else if (i < E + IE) {
        atomicAdd(&counts_u[iu[i - E]], 1);
    }
}

// ---- hierarchical exclusive scan (both arrays in one set of launches) --

__global__ __launch_bounds__(SCAN_B) void k_scan1(
    const int* __restrict__ ce, int* __restrict__ oe, int* __restrict__ be,
    int nE, int nbE,
    const int* __restrict__ cu, int* __restrict__ ou, int* __restrict__ bu,
    int nU) {
    __shared__ int tmp[SCAN_B];
    const int* in; int* out; int* bs; int n; int lb;
    if ((int)blockIdx.x < nbE) { in = ce; out = oe; bs = be; n = nE; lb = blockIdx.x; }
    else { in = cu; out = ou; bs = bu; n = nU; lb = blockIdx.x - nbE; }
    int i = lb * SCAN_B + threadIdx.x;
    int v = (i < n) ? in[i] : 0;
    tmp[threadIdx.x] = v;
    __syncthreads();
    for (int o = 1; o < SCAN_B; o <<= 1) {
        int t = (threadIdx.x >= (unsigned)o) ? tmp[threadIdx.x - o] : 0;
        __syncthreads();
        tmp[threadIdx.x] += t;
        __syncthreads();
    }
    if (i < n) out[i] = tmp[threadIdx.x] - v;   // exclusive
    if (threadIdx.x == SCAN_B - 1) bs[lb] = tmp[threadIdx.x];
}

__global__ __launch_bounds__(1024) void k_scan2(
    int* __restrict__ be, int nbE, int* __restrict__ bu, int nbU) {
    __shared__ int tmp[1024];
    int* bs = (blockIdx.x == 0) ? be : bu;
    int nb  = (blockIdx.x == 0) ? nbE : nbU;
    int v = ((int)threadIdx.x < nb) ? bs[threadIdx.x] : 0;
    tmp[threadIdx.x] = v;
    __syncthreads();
    for (int o = 1; o < 1024; o <<= 1) {
        int t = (threadIdx.x >= (unsigned)o) ? tmp[threadIdx.x - o] : 0;
        __syncthreads();
        tmp[threadIdx.x] += t;
        __syncthreads();
    }
    if ((int)threadIdx.x < nb) bs[threadIdx.x] = tmp[threadIdx.x] - v;  // exclusive
}

__global__ __launch_bounds__(SCAN_B) void k_scan3(
    int* __restrict__ oe, int* __restrict__ cure, const int* __restrict__ be,
    int nE, int nbE,
    int* __restrict__ ou, int* __restrict__ curu, const int* __restrict__ bu,
    int nU) {
    int* out; int* cur; const int* bs; int n; int lb;
    if ((int)blockIdx.x < nbE) { out = oe; cur = cure; bs = be; n = nE; lb = blockIdx.x; }
    else { out = ou; cur = curu; bs = bu; n = nU; lb = blockIdx.x - nbE; }
    int i = lb * SCAN_B + threadIdx.x;
    if (i < n) {
        int v = out[i] + bs[lb];
        out[i] = v;
        cur[i] = v;
    }
}

// ---- fused CSR fill (packed metadata) ---------------------------------

__global__ __launch_bounds__(256) void k_fill_both(
    const int* __restrict__ head, const int* __restrict__ tail,
    const int* __restrict__ etype, const float* __restrict__ omega,
    const int* __restrict__ iu, const int* __restrict__ ii,
    const float* __restrict__ iw,
    int* __restrict__ cursor_e, int* __restrict__ cursor_u,
    int4* __restrict__ kg, int2* __restrict__ uc, int E, int IE) {
    int i = blockIdx.x * blockDim.x + threadIdx.x;
    if (i < E) {
        int h = head[i];
        int p = atomicAdd(&cursor_e[h], 1);
        int4 m;
        m.x = tail[i];
        m.y = etype[i] - 1;
        m.z = __float_as_int(omega[i]);
        m.w = 0;
        kg[p] = m;
    } else if (i < E + IE) {
        int e = i - E;
        int u = iu[e];
        int p = atomicAdd(&cursor_u[u], 1);
        int2 m;
        m.x = ii[e];
        m.y = __float_as_int(iw[e]);
        uc[p] = m;
    }
}

// ---- attention: rewrite kg.z=alpha, kg.w=eta in place ------------------

__global__ __launch_bounds__(256) void k_attn(
    const int* __restrict__ offs, const int* __restrict__ counts,
    int4* __restrict__ kg, int n) {
    int h = blockIdx.x * blockDim.x + threadIdx.x;
    if (h >= n) return;
    int s = offs[h], deg = counts[h];
    float sum = 0.0f;
    for (int j = s; j < s + deg; ++j) sum += __int_as_float(kg[j].z);
    float den = sum + EPSV;
    float sum2 = 0.0f;
    for (int j = s; j < s + deg; ++j) {
        int4 m = kg[j];
        float a = __int_as_float(m.z) / den;
        m.z = __float_as_int(a);
        kg[j] = m;
        sum2 += (a > GAMMAV) ? a : 0.0f;
    }
    float den2 = sum2 + EPSV;
    for (int j = s; j < s + deg; ++j) {
        int4 m = kg[j];
        float a = __int_as_float(m.z);
        float e0 = (a > GAMMAV) ? a : 0.0f;
        m.w = __float_as_int(e0 / den2);
        kg[j] = m;
    }
}

// ---- fused hop: ent gather + usr gather in one dispatch ----------------
// waves [0, n_ent)            : entity rows
// waves [n_ent, n_ent+n_users): user rows
// hop 1: ent y -> ent_out;  usr_res  = user_emb + y
// hop 2: ent y -> ent_out;  usr_res += y
// hop 3: ent_res = ent0 + y1 + y2 + y (rho=eta);  usr_res += y

__global__ __launch_bounds__(256) void k_hop(
    const int* __restrict__ offs_e, const int* __restrict__ cnt_e,
    const int4* __restrict__ kg,
    const int* __restrict__ offs_u, const int* __restrict__ cnt_u,
    const int2* __restrict__ uc,
    const float* __restrict__ rel,
    const float* __restrict__ src,   // entity features this hop
    const float* __restrict__ ent0,  // entity_emb   (hop3)
    const float* __restrict__ y1,    // ent_a        (hop3)
    const float* __restrict__ y2,    // ent_b        (hop3)
    float* __restrict__ ent_out,     // ent_a / ent_b / ent_res
    const float* __restrict__ user0, // user_emb
    float* __restrict__ usr_res,
    int n_ent, int n_users, int hop) {
    int row  = (int)((blockIdx.x * (size_t)blockDim.x + threadIdx.x) >> 6);
    int lane = threadIdx.x & 63;
    if (row < n_ent) {
        int s = offs_e[row], deg = cnt_e[row];
        int end = s + deg;
        float4 acc = make_float4(0.f, 0.f, 0.f, 0.f);
        int4 m = (deg > 0) ? kg[s] : make_int4(0, 0, 0, 0);
        for (int j = s; j < end; ++j) {
            int4 mc = m;
            if (j + 1 < end) m = kg[j + 1];      // prefetch next edge meta
            float4 ev = ((const float4*)(src + (size_t)mc.x * D))[lane];
            float4 rw = ((const float4*)(rel + (size_t)mc.y * D))[lane];
            float rv = (hop == 3) ? __int_as_float(mc.w) : __int_as_float(mc.z);
            acc.x += rv * ev.x * rw.x;
            acc.y += rv * ev.y * rw.y;
            acc.z += rv * ev.z * rw.z;
            acc.w += rv * ev.w * rw.w;
        }
        float c = (deg > 0) ? (float)deg : 1.0f;
        acc.x /= c; acc.y /= c; acc.z /= c; acc.w /= c;
        float ss = acc.x * acc.x + acc.y * acc.y + acc.z * acc.z + acc.w * acc.w;
        #pragma unroll
        for (int o = 32; o >= 1; o >>= 1) ss += __shfl_down(ss, o);
        ss = __shfl(ss, 0);
        float nrm = sqrtf(ss);
        float dn = (nrm > EPSV) ? nrm : EPSV;
        float4 y;
        y.x = cleanf(acc.x / dn);
        y.y = cleanf(acc.y / dn);
        y.z = cleanf(acc.z / dn);
        y.w = cleanf(acc.w / dn);
        if (hop == 3) {
            float4 a0 = ((const float4*)(ent0 + (size_t)row * D))[lane];
            float4 a1 = ((const float4*)(y1 + (size_t)row * D))[lane];
            float4 a2 = ((const float4*)(y2 + (size_t)row * D))[lane];
            y.x += a0.x + a1.x + a2.x;
            y.y += a0.y + a1.y + a2.y;
            y.z += a0.z + a1.z + a2.z;
            y.w += a0.w + a1.w + a2.w;
        }
        ((float4*)(ent_out + (size_t)row * D))[lane] = y;
    } else {
        int u = row - n_ent;
        if (u >= n_users) return;
        int s = offs_u[u], deg = cnt_u[u];
        int end = s + deg;
        float4 acc = make_float4(0.f, 0.f, 0.f, 0.f);
        int2 m = (deg > 0) ? uc[s] : make_int2(0, 0);
        for (int j = s; j < end; ++j) {
            int2 mc = m;
            if (j + 1 < end) m = uc[j + 1];
            float4 ev = ((const float4*)(src + (size_t)mc.x * D))[lane];
            float wv = __int_as_float(mc.y);
            acc.x += wv * ev.x;
            acc.y += wv * ev.y;
            acc.z += wv * ev.z;
            acc.w += wv * ev.w;
        }
        float ss = acc.x * acc.x + acc.y * acc.y + acc.z * acc.z + acc.w * acc.w;
        #pragma unroll
        for (int o = 32; o >= 1; o >>= 1) ss += __shfl_down(ss, o);
        ss = __shfl(ss, 0);
        float nrm = sqrtf(ss);
        float dn = (nrm > EPSV) ? nrm : EPSV;
        float4 y;
        y.x = cleanf(acc.x / dn);
        y.y = cleanf(acc.y / dn);
        y.z = cleanf(acc.z / dn);
        y.w = cleanf(acc.w / dn);
        float4 base;
        if (hop == 1) base = ((const float4*)(user0 + (size_t)u * D))[lane];
        else          base = ((const float4*)(usr_res + (size_t)u * D))[lane];
        y.x += base.x; y.y += base.y; y.z += base.z; y.w += base.w;
        ((float4*)(usr_res + (size_t)u * D))[lane] = y;
    }
}

extern "C" void kernel_launch(void* const* d_in, const int* in_sizes, int n_in,
                              void* d_out, int out_size, void* d_ws, size_t ws_size,
                              hipStream_t stream) {
    const float* user_emb   = (const float*)d_in[0];
    const float* entity_emb = (const float*)d_in[1];
    const int*   edge_index = (const int*)d_in[2];
    const int*   edge_type  = (const int*)d_in[3];
    const float* omega      = (const float*)d_in[4];
    const int*   inter_edge = (const int*)d_in[5];
    const float* inter_w    = (const float*)d_in[6];
    const float* rel_emb    = (const float*)d_in[7];

    const int n_users = in_sizes[0] / D;
    const int n_ent   = in_sizes[1] / D;
    const int E       = in_sizes[3];
    const int IE      = in_sizes[6];

    const int* head = edge_index;
    const int* tail = edge_index + E;
    const int* iu   = inter_edge;
    const int* ii   = inter_edge + IE;

    // ---- workspace layout (16B-aligned chunks) ----
    char* w = (char*)d_ws;
    size_t entB = (size_t)n_ent * D * sizeof(float);
    float* ent_a = (float*)w;  w += entB;
    float* ent_b = (float*)w;  w += entB;
    int4*  kg    = (int4*)w;   w += (size_t)E * sizeof(int4);
    int2*  ucsr  = (int2*)w;   w += (size_t)IE * sizeof(int2);
    int*   counts_e = (int*)w; w += (size_t)n_ent * sizeof(int);
    int*   counts_u = (int*)w; w += (size_t)n_users * sizeof(int);
    int*   offs_e   = (int*)w; w += (size_t)n_ent * sizeof(int);
    int*   offs_u   = (int*)w; w += (size_t)n_users * sizeof(int);
    int*   cursor_e = (int*)w; w += (size_t)n_ent * sizeof(int);
    int*   cursor_u = (int*)w; w += (size_t)n_users * sizeof(int);
    int*   bsums_e  = (int*)w; w += 1024 * sizeof(int);
    int*   bsums_u  = (int*)w; w += 1024 * sizeof(int);

    float* ent_res = (float*)d_out;
    float* usr_res = (float*)d_out + (size_t)n_ent * D;

    // ---- init: zero both count arrays in one memset (adjacent) ----
    hipMemsetAsync(counts_e, 0, ((size_t)n_ent + n_users) * sizeof(int), stream);

    int total_edges = E + IE;
    int eb = (total_edges + 255) / 256;

    // ---- counts ----
    k_count_both<<<eb, 256, 0, stream>>>(head, iu, counts_e, counts_u, E, IE);

    // ---- exclusive scans -> offsets (+cursors) ----
    int nbE = (n_ent + SCAN_B - 1) / SCAN_B;
    int nbU = (n_users + SCAN_B - 1) / SCAN_B;
    k_scan1<<<nbE + nbU, SCAN_B, 0, stream>>>(counts_e, offs_e, bsums_e, n_ent, nbE,
                                              counts_u, offs_u, bsums_u, n_users);
    k_scan2<<<2, 1024, 0, stream>>>(bsums_e, nbE, bsums_u, nbU);
    k_scan3<<<nbE + nbU, SCAN_B, 0, stream>>>(offs_e, cursor_e, bsums_e, n_ent, nbE,
                                              offs_u, cursor_u, bsums_u, n_users);

    // ---- fill CSR (packed) ----
    k_fill_both<<<eb, 256, 0, stream>>>(head, tail, edge_type, omega, iu, ii,
                                        inter_w, cursor_e, cursor_u, kg, ucsr,
                                        E, IE);

    // ---- attention (alpha/eta into kg.z/kg.w) ----
    int hb = (n_ent + 255) / 256;
    k_attn<<<hb, 256, 0, stream>>>(offs_e, counts_e, kg, n_ent);

    // ---- hops ----
    size_t waves = (size_t)n_ent + n_users;
    int gb = (int)((waves * 64 + 255) / 256);

    // hop 1: src=entity_emb, ent y->ent_a, usr_res=user_emb+y
    k_hop<<<gb, 256, 0, stream>>>(offs_e, counts_e, kg, offs_u, counts_u, ucsr,
                                  rel_emb, entity_emb, entity_emb, ent_a, ent_b,
                                  ent_a, user_emb, usr_res, n_ent, n_users, 1);
    // hop 2: src=ent_a, ent y->ent_b, usr_res+=y
    k_hop<<<gb, 256, 0, stream>>>(offs_e, counts_e, kg, offs_u, counts_u, ucsr,
                                  rel_emb, ent_a, entity_emb, ent_a, ent_b,
                                  ent_b, user_emb, usr_res, n_ent, n_users, 2);
    // hop 3: src=ent_b, ent_res=ent0+y1+y2+y (eta), usr_res+=y
    k_hop<<<gb, 256, 0, stream>>>(offs_e, counts_e, kg, offs_u, counts_u, ucsr,
                                  rel_emb, ent_b, entity_emb, ent_a, ent_b,
                                  ent_res, user_emb, usr_res, n_ent, n_users, 3);
}

// Round 4
// 636.801 us; speedup vs baseline: 10.4976x; 1.1242x over previous
//
#include <hip/hip_runtime.h>
#include <math.h>

#define D 256
#define EPSV 1e-8f
#define GAMMAV 0.2f
#define SCAN_B 256

__device__ __forceinline__ float cleanf(float x) {
    if (isnan(x)) return 0.0f;
    if (isinf(x)) return x > 0.0f ? 10000.0f : 0.0001f;
    return x;
}

// bf16 <-> f32 (RNE on the way down; exact on the way up)
__device__ __forceinline__ unsigned short f2bf(float x) {
    unsigned u = __float_as_uint(x);
    return (unsigned short)((u + 0x7FFFu + ((u >> 16) & 1u)) >> 16);
}
__device__ __forceinline__ float bf2f(unsigned short b) {
    return __uint_as_float(((unsigned)b) << 16);
}

// ---- fp32 -> bf16 table convert ---------------------------------------

__global__ __launch_bounds__(256) void k_convert(
    const float4* __restrict__ in, ushort4* __restrict__ out, int n4) {
    int i = blockIdx.x * blockDim.x + threadIdx.x;
    if (i >= n4) return;
    float4 v = in[i];
    out[i] = make_ushort4(f2bf(v.x), f2bf(v.y), f2bf(v.z), f2bf(v.w));
}

// ---- counting + omega denominator -------------------------------------

__global__ __launch_bounds__(256) void k_count_both(
    const int* __restrict__ head, const float* __restrict__ omega,
    const int* __restrict__ iu,
    int* __restrict__ counts_e, int* __restrict__ counts_u,
    float* __restrict__ denom, int E, int IE) {
    int i = blockIdx.x * blockDim.x + threadIdx.x;
    if (i < E) {
        int h = head[i];
        atomicAdd(&counts_e[h], 1);
        atomicAdd(&denom[h], omega[i]);
    } else if (i < E + IE) {
        atomicAdd(&counts_u[iu[i - E]], 1);
    }
}

// ---- hierarchical exclusive scan (both arrays, one launch set) --------

__global__ __launch_bounds__(SCAN_B) void k_scan1(
    const int* __restrict__ ce, int* __restrict__ oe, int* __restrict__ be,
    int nE, int nbE,
    const int* __restrict__ cu, int* __restrict__ ou, int* __restrict__ bu,
    int nU) {
    __shared__ int tmp[SCAN_B];
    const int* in; int* out; int* bs; int n; int lb;
    if ((int)blockIdx.x < nbE) { in = ce; out = oe; bs = be; n = nE; lb = blockIdx.x; }
    else { in = cu; out = ou; bs = bu; n = nU; lb = blockIdx.x - nbE; }
    int i = lb * SCAN_B + threadIdx.x;
    int v = (i < n) ? in[i] : 0;
    tmp[threadIdx.x] = v;
    __syncthreads();
    for (int o = 1; o < SCAN_B; o <<= 1) {
        int t = (threadIdx.x >= (unsigned)o) ? tmp[threadIdx.x - o] : 0;
        __syncthreads();
        tmp[threadIdx.x] += t;
        __syncthreads();
    }
    if (i < n) out[i] = tmp[threadIdx.x] - v;   // exclusive
    if (threadIdx.x == SCAN_B - 1) bs[lb] = tmp[threadIdx.x];
}

__global__ __launch_bounds__(1024) void k_scan2(
    int* __restrict__ be, int nbE, int* __restrict__ bu, int nbU) {
    __shared__ int tmp[1024];
    int* bs = (blockIdx.x == 0) ? be : bu;
    int nb  = (blockIdx.x == 0) ? nbE : nbU;
    int v = ((int)threadIdx.x < nb) ? bs[threadIdx.x] : 0;
    tmp[threadIdx.x] = v;
    __syncthreads();
    for (int o = 1; o < 1024; o <<= 1) {
        int t = (threadIdx.x >= (unsigned)o) ? tmp[threadIdx.x - o] : 0;
        __syncthreads();
        tmp[threadIdx.x] += t;
        __syncthreads();
    }
    if ((int)threadIdx.x < nb) bs[threadIdx.x] = tmp[threadIdx.x] - v;  // exclusive
}

__global__ __launch_bounds__(SCAN_B) void k_scan3(
    int* __restrict__ oe, int* __restrict__ cure, const int* __restrict__ be,
    int nE, int nbE,
    int* __restrict__ ou, int* __restrict__ curu, const int* __restrict__ bu,
    int nU) {
    int* out; int* cur; const int* bs; int n; int lb;
    if ((int)blockIdx.x < nbE) { out = oe; cur = cure; bs = be; n = nE; lb = blockIdx.x; }
    else { out = ou; cur = curu; bs = bu; n = nU; lb = blockIdx.x - nbE; }
    int i = lb * SCAN_B + threadIdx.x;
    if (i < n) {
        int v = out[i] + bs[lb];
        out[i] = v;
        cur[i] = v;
    }
}

// ---- CSR fill: packed meta + inline alpha + eta denominator -----------

__global__ __launch_bounds__(256) void k_fill_both(
    const int* __restrict__ head, const int* __restrict__ tail,
    const int* __restrict__ etype, const float* __restrict__ omega,
    const int* __restrict__ iu, const int* __restrict__ ii,
    const float* __restrict__ iw,
    const float* __restrict__ denom, float* __restrict__ denom2,
    int* __restrict__ cursor_e, int* __restrict__ cursor_u,
    int2* __restrict__ kg, int2* __restrict__ uc, int E, int IE) {
    int i = blockIdx.x * blockDim.x + threadIdx.x;
    if (i < E) {
        int h = head[i];
        float a = omega[i] / (denom[h] + EPSV);
        int p = atomicAdd(&cursor_e[h], 1);
        int2 m;
        m.x = tail[i] | ((etype[i] - 1) << 20);   // tail < 2^20, rel < 2^5
        m.y = __float_as_int(a);
        kg[p] = m;
        if (a > GAMMAV) atomicAdd(&denom2[h], a);
    } else if (i < E + IE) {
        int e = i - E;
        int u = iu[e];
        int p = atomicAdd(&cursor_u[u], 1);
        int2 m;
        m.x = ii[e];
        m.y = __float_as_int(iw[e]);
        uc[p] = m;
    }
}

// ---- fused hop: ent gather + usr gather in one dispatch ----------------
// waves [0, n_ent)            : entity rows (bf16 src -> bf16 dst, hop3 fp32 res)
// waves [n_ent, n_ent+n_users): user rows   (bf16 src -> fp32 usr_res RMW)

__global__ __launch_bounds__(256) void k_hop(
    const int* __restrict__ offs_e, const int* __restrict__ cnt_e,
    const int2* __restrict__ kg,
    const int* __restrict__ offs_u, const int* __restrict__ cnt_u,
    const int2* __restrict__ uc,
    const float* __restrict__ denom2,
    const float* __restrict__ rel,              // fp32 (tiny, cached)
    const unsigned short* __restrict__ src,     // bf16 entity features
    const unsigned short* __restrict__ ent0b,   // bf16 entity_emb (hop3)
    const unsigned short* __restrict__ y1b,     // bf16 hop-1 output (hop3)
    const unsigned short* __restrict__ y2b,     // bf16 hop-2 output (hop3)
    unsigned short* __restrict__ ent_out_b,     // bf16 dst (hops 1,2)
    float* __restrict__ ent_res,                // fp32 dst (hop3)
    const float* __restrict__ user0,
    float* __restrict__ usr_res,
    int n_ent, int n_users, int hop) {
    int row  = (int)((blockIdx.x * (size_t)blockDim.x + threadIdx.x) >> 6);
    int lane = threadIdx.x & 63;
    if (row < n_ent) {
        int s = offs_e[row], deg = cnt_e[row];
        int end = s + deg;
        float den2;
        if (hop == 3) den2 = denom2[row] + EPSV;
        float4 acc = make_float4(0.f, 0.f, 0.f, 0.f);
        int2 m = (deg > 0) ? kg[s] : make_int2(0, 0);
        for (int j = s; j < end; ++j) {
            int2 mc = m;
            if (j + 1 < end) m = kg[j + 1];          // prefetch next meta
            int t = mc.x & 0xFFFFF;
            int r = ((unsigned)mc.x) >> 20;
            float a = __int_as_float(mc.y);
            float rv;
            if (hop == 3) { float e0 = (a > GAMMAV) ? a : 0.0f; rv = e0 / den2; }
            else rv = a;
            ushort4 eb = ((const ushort4*)(src + (size_t)t * D))[lane];
            float4 rw = ((const float4*)(rel + (size_t)r * D))[lane];
            acc.x += rv * bf2f(eb.x) * rw.x;
            acc.y += rv * bf2f(eb.y) * rw.y;
            acc.z += rv * bf2f(eb.z) * rw.z;
            acc.w += rv * bf2f(eb.w) * rw.w;
        }
        float c = (deg > 0) ? (float)deg : 1.0f;
        acc.x /= c; acc.y /= c; acc.z /= c; acc.w /= c;
        float ss = acc.x * acc.x + acc.y * acc.y + acc.z * acc.z + acc.w * acc.w;
        #pragma unroll
        for (int o = 32; o >= 1; o >>= 1) ss += __shfl_down(ss, o);
        ss = __shfl(ss, 0);
        float nrm = sqrtf(ss);
        float dn = (nrm > EPSV) ? nrm : EPSV;
        float4 y;
        y.x = cleanf(acc.x / dn);
        y.y = cleanf(acc.y / dn);
        y.z = cleanf(acc.z / dn);
        y.w = cleanf(acc.w / dn);
        if (hop == 3) {
            ushort4 a0 = ((const ushort4*)(ent0b + (size_t)row * D))[lane];
            ushort4 a1 = ((const ushort4*)(y1b  + (size_t)row * D))[lane];
            ushort4 a2 = ((const ushort4*)(y2b  + (size_t)row * D))[lane];
            y.x += bf2f(a0.x) + bf2f(a1.x) + bf2f(a2.x);
            y.y += bf2f(a0.y) + bf2f(a1.y) + bf2f(a2.y);
            y.z += bf2f(a0.z) + bf2f(a1.z) + bf2f(a2.z);
            y.w += bf2f(a0.w) + bf2f(a1.w) + bf2f(a2.w);
            ((float4*)(ent_res + (size_t)row * D))[lane] = y;
        } else {
            ((ushort4*)(ent_out_b + (size_t)row * D))[lane] =
                make_ushort4(f2bf(y.x), f2bf(y.y), f2bf(y.z), f2bf(y.w));
        }
    } else {
        int u = row - n_ent;
        if (u >= n_users) return;
        int s = offs_u[u], deg = cnt_u[u];
        int end = s + deg;
        float4 acc = make_float4(0.f, 0.f, 0.f, 0.f);
        int2 m = (deg > 0) ? uc[s] : make_int2(0, 0);
        for (int j = s; j < end; ++j) {
            int2 mc = m;
            if (j + 1 < end) m = uc[j + 1];
            ushort4 eb = ((const ushort4*)(src + (size_t)mc.x * D))[lane];
            float wv = __int_as_float(mc.y);
            acc.x += wv * bf2f(eb.x);
            acc.y += wv * bf2f(eb.y);
            acc.z += wv * bf2f(eb.z);
            acc.w += wv * bf2f(eb.w);
        }
        float ss = acc.x * acc.x + acc.y * acc.y + acc.z * acc.z + acc.w * acc.w;
        #pragma unroll
        for (int o = 32; o >= 1; o >>= 1) ss += __shfl_down(ss, o);
        ss = __shfl(ss, 0);
        float nrm = sqrtf(ss);
        float dn = (nrm > EPSV) ? nrm : EPSV;
        float4 y;
        y.x = cleanf(acc.x / dn);
        y.y = cleanf(acc.y / dn);
        y.z = cleanf(acc.z / dn);
        y.w = cleanf(acc.w / dn);
        float4 base;
        if (hop == 1) base = ((const float4*)(user0 + (size_t)u * D))[lane];
        else          base = ((const float4*)(usr_res + (size_t)u * D))[lane];
        y.x += base.x; y.y += base.y; y.z += base.z; y.w += base.w;
        ((float4*)(usr_res + (size_t)u * D))[lane] = y;
    }
}

extern "C" void kernel_launch(void* const* d_in, const int* in_sizes, int n_in,
                              void* d_out, int out_size, void* d_ws, size_t ws_size,
                              hipStream_t stream) {
    const float* user_emb   = (const float*)d_in[0];
    const float* entity_emb = (const float*)d_in[1];
    const int*   edge_index = (const int*)d_in[2];
    const int*   edge_type  = (const int*)d_in[3];
    const float* omega      = (const float*)d_in[4];
    const int*   inter_edge = (const int*)d_in[5];
    const float* inter_w    = (const float*)d_in[6];
    const float* rel_emb    = (const float*)d_in[7];

    const int n_users = in_sizes[0] / D;
    const int n_ent   = in_sizes[1] / D;
    const int E       = in_sizes[3];
    const int IE      = in_sizes[6];

    const int* head = edge_index;
    const int* tail = edge_index + E;
    const int* iu   = inter_edge;
    const int* ii   = inter_edge + IE;

    // ---- workspace layout ----
    char* w = (char*)d_ws;
    size_t entBh = (size_t)n_ent * D * sizeof(unsigned short);   // bf16 table
    unsigned short* ent0b = (unsigned short*)w;  w += entBh;
    unsigned short* ent_a = (unsigned short*)w;  w += entBh;
    unsigned short* ent_b = (unsigned short*)w;  w += entBh;
    int2*  kg    = (int2*)w;   w += (size_t)E * sizeof(int2);
    int2*  ucsr  = (int2*)w;   w += (size_t)IE * sizeof(int2);
    // zero-init region: counts_e | counts_u | denom | denom2 (contiguous)
    int*   counts_e = (int*)w;   w += (size_t)n_ent * sizeof(int);
    int*   counts_u = (int*)w;   w += (size_t)n_users * sizeof(int);
    float* denom    = (float*)w; w += (size_t)n_ent * sizeof(float);
    float* denom2   = (float*)w; w += (size_t)n_ent * sizeof(float);
    size_t zeroB = ((size_t)n_ent * 3 + n_users) * sizeof(int);
    int*   offs_e   = (int*)w; w += (size_t)n_ent * sizeof(int);
    int*   offs_u   = (int*)w; w += (size_t)n_users * sizeof(int);
    int*   cursor_e = (int*)w; w += (size_t)n_ent * sizeof(int);
    int*   cursor_u = (int*)w; w += (size_t)n_users * sizeof(int);
    int*   bsums_e  = (int*)w; w += 1024 * sizeof(int);
    int*   bsums_u  = (int*)w; w += 1024 * sizeof(int);

    float* ent_res = (float*)d_out;
    float* usr_res = (float*)d_out + (size_t)n_ent * D;

    hipMemsetAsync(counts_e, 0, zeroB, stream);

    // ---- bf16 convert of entity_emb ----
    int n4 = n_ent * (D / 4);
    k_convert<<<(n4 + 255) / 256, 256, 0, stream>>>(
        (const float4*)entity_emb, (ushort4*)ent0b, n4);

    int total_edges = E + IE;
    int eb = (total_edges + 255) / 256;

    // ---- counts + omega denominators ----
    k_count_both<<<eb, 256, 0, stream>>>(head, omega, iu, counts_e, counts_u,
                                         denom, E, IE);

    // ---- exclusive scans -> offsets (+cursors) ----
    int nbE = (n_ent + SCAN_B - 1) / SCAN_B;
    int nbU = (n_users + SCAN_B - 1) / SCAN_B;
    k_scan1<<<nbE + nbU, SCAN_B, 0, stream>>>(counts_e, offs_e, bsums_e, n_ent, nbE,
                                              counts_u, offs_u, bsums_u, n_users);
    k_scan2<<<2, 1024, 0, stream>>>(bsums_e, nbE, bsums_u, nbU);
    k_scan3<<<nbE + nbU, SCAN_B, 0, stream>>>(offs_e, cursor_e, bsums_e, n_ent, nbE,
                                              offs_u, cursor_u, bsums_u, n_users);

    // ---- fill CSR (packed, alpha inline, eta denominator) ----
    k_fill_both<<<eb, 256, 0, stream>>>(head, tail, edge_type, omega, iu, ii,
                                        inter_w, denom, denom2,
                                        cursor_e, cursor_u, kg, ucsr, E, IE);

    // ---- hops ----
    size_t waves = (size_t)n_ent + n_users;
    int gb = (int)((waves * 64 + 255) / 256);

    // hop 1: src=ent0b -> ent_a;  usr_res = user_emb + y
    k_hop<<<gb, 256, 0, stream>>>(offs_e, counts_e, kg, offs_u, counts_u, ucsr,
                                  denom2, rel_emb, ent0b, ent0b, ent_a, ent_b,
                                  ent_a, ent_res, user_emb, usr_res,
                                  n_ent, n_users, 1);
    // hop 2: src=ent_a -> ent_b;  usr_res += y
    k_hop<<<gb, 256, 0, stream>>>(offs_e, counts_e, kg, offs_u, counts_u, ucsr,
                                  denom2, rel_emb, ent_a, ent0b, ent_a, ent_b,
                                  ent_b, ent_res, user_emb, usr_res,
                                  n_ent, n_users, 2);
    // hop 3: src=ent_b; ent_res = ent0 + y1 + y2 + y (eta);  usr_res += y
    k_hop<<<gb, 256, 0, stream>>>(offs_e, counts_e, kg, offs_u, counts_u, ucsr,
                                  denom2, rel_emb, ent_b, ent0b, ent_a, ent_b,
                                  ent_b /*unused*/, ent_res, user_emb, usr_res,
                                  n_ent, n_users, 3);
}